// Round 15
// baseline (473.214 us; speedup 1.0000x reference)
//
#include <hip/hip_runtime.h>
#include <stdint.h>

// EETQLinear w8a16: out[m,n] = (sum_k x[m,k]*wq[k,n]) * scale[n] + bias[n]
// M=8192, K=4096, N=4096. Dtypes (r3/r4-verified): x/scale/bias/out f32, wq int32.
// v15: r7 GEMM skeleton VERBATIM (best measured: 228us GEMM), but the convert_x
//      prologue is FUSED into the GEMM: A is loaded as f32 into regs one tile
//      ahead, cvt->f16 at tile tail, ds_write with the read-side XOR involution.
//      B-path (dequant_w prologue + global_load_lds staging) unchanged.

typedef __attribute__((ext_vector_type(4))) float     f32x4;
typedef __attribute__((ext_vector_type(8))) _Float16  f16x8;

#define M_DIM 8192
#define N_DIM 4096
#define K_DIM 4096

// ---------------- prologue: wq int32 [K][N] -> Wt f16 [N][K] (r4-verified) -------
__global__ __launch_bounds__(256) void dequant_w_to_f16(const int* __restrict__ wq,
                                                        _Float16* __restrict__ Wt) {
    __shared__ _Float16 tile[64][65];
    const int n0 = blockIdx.x * 64;
    const int k0 = blockIdx.y * 64;
    const int t  = threadIdx.x;
    const int r  = t >> 2;
    const int c0 = (t & 3) * 16;
    const int* src = wq + (size_t)(k0 + r) * N_DIM + n0 + c0;
#pragma unroll
    for (int j = 0; j < 4; ++j) {
        int4 q = *(const int4*)(src + j * 4);
        tile[c0 + j * 4 + 0][r] = (_Float16)q.x;
        tile[c0 + j * 4 + 1][r] = (_Float16)q.y;
        tile[c0 + j * 4 + 2][r] = (_Float16)q.z;
        tile[c0 + j * 4 + 3][r] = (_Float16)q.w;
    }
    __syncthreads();
    const int nn  = t >> 2;
    const int cc0 = (t & 3) * 16;
    _Float16 vals[16] __attribute__((aligned(16)));
#pragma unroll
    for (int j = 0; j < 16; ++j) vals[j] = tile[nn][cc0 + j];
    _Float16* dst = Wt + (size_t)(n0 + nn) * K_DIM + k0 + cc0;
    *(float4*)(dst + 0) = *(const float4*)(vals + 0);
    *(float4*)(dst + 8) = *(const float4*)(vals + 8);
}

// ---------------- GEMM: r7 skeleton + fused A-conversion ----------------
#define AS1C(p) (const __attribute__((address_space(1))) void*)(p)
#define AS3C(p) (__attribute__((address_space(3))) void*)(p)

// B staging (r7 verbatim): thread t covers rows (t>>3)+{0,64} of each 128-row
// half, 16B k-slot t&7; SOURCE k pre-XORed by ((row&7)<<4); LDS dest linear.
#define STAGE_B(arr, h, tile) do {                                                    \
    __builtin_amdgcn_global_load_lds(                                                 \
        AS1C(bStageBase + (size_t)((h) * 128) * K_DIM + (tile) * 64),                 \
        AS3C((char*)(arr) + (h) * 16384 + t * 16), 16, 0, 0);                         \
    __builtin_amdgcn_global_load_lds(                                                 \
        AS1C(bStageBase + (size_t)((h) * 128 + 64) * K_DIM + (tile) * 64),            \
        AS3C((char*)(arr) + (h) * 16384 + 8192 + t * 16), 16, 0, 0);                  \
} while (0)

// A: load tile tl's f32 into av[8] (consumed one tile later)
#define LOAD_A(tl) do {                                                               \
    const float4* ap_ = (const float4*)(aSrc + (size_t)(tl) * 64);                    \
    _Pragma("unroll")                                                                 \
    for (int j_ = 0; j_ < 8; ++j_) av[j_] = ap_[j_];                                  \
} while (0)

// A: cvt av -> f16 and ds_write 4x16B into buffer base P, chunks XOR-swizzled
// to match the read-side involution (byte_in_row = k_byte ^ ((row&7)<<4)).
#define WRITE_A(P) do {                                                               \
    _Pragma("unroll")                                                                 \
    for (int j_ = 0; j_ < 4; ++j_) {                                                  \
        f16x8 h_;                                                                     \
        h_[0] = (_Float16)av[2 * j_].x;     h_[1] = (_Float16)av[2 * j_].y;           \
        h_[2] = (_Float16)av[2 * j_].z;     h_[3] = (_Float16)av[2 * j_].w;           \
        h_[4] = (_Float16)av[2 * j_ + 1].x; h_[5] = (_Float16)av[2 * j_ + 1].y;       \
        h_[6] = (_Float16)av[2 * j_ + 1].z; h_[7] = (_Float16)av[2 * j_ + 1].w;       \
        *(f16x8*)((P) + (((akh4 + j_) * 16) ^ aswz)) = h_;                            \
    }                                                                                 \
} while (0)

#define DSR(dst, addr, IMM) \
    asm volatile("ds_read_b128 %0, %1 offset:%c2" : "=v"(dst) : "v"(addr), "i"(IMM))

#define DSRA(S, Q, A0, A1)                   \
    DSR(S[0][0], A0, (Q) * 4096);            \
    DSR(S[0][1], A1, (Q) * 4096);            \
    DSR(S[1][0], A0, (Q) * 4096 + 2048);     \
    DSR(S[1][1], A1, (Q) * 4096 + 2048)

#define DSRB(BA0, BA1)                       \
    DSR(bf[0][0], BA0, 0);    DSR(bf[0][1], BA1, 0);    \
    DSR(bf[1][0], BA0, 2048); DSR(bf[1][1], BA1, 2048); \
    DSR(bf[2][0], BA0, 4096); DSR(bf[2][1], BA1, 4096); \
    DSR(bf[3][0], BA0, 6144); DSR(bf[3][1], BA1, 6144)

#define MMS(S, AI, N)                                                                 \
    acc[AI][N] = __builtin_amdgcn_mfma_f32_16x16x32_f16(S[(AI) & 1][0], bf[N][0],     \
                                                        acc[AI][N], 0, 0, 0);         \
    acc[AI][N] = __builtin_amdgcn_mfma_f32_16x16x32_f16(S[(AI) & 1][1], bf[N][1],     \
                                                        acc[AI][N], 0, 0, 0)

#define MFMA16(Q, S)                                                  \
    MMS(S, (Q) * 2 + 0, 0); MMS(S, (Q) * 2 + 0, 1);                   \
    MMS(S, (Q) * 2 + 0, 2); MMS(S, (Q) * 2 + 0, 3);                   \
    MMS(S, (Q) * 2 + 1, 0); MMS(S, (Q) * 2 + 1, 1);                   \
    MMS(S, (Q) * 2 + 1, 2); MMS(S, (Q) * 2 + 1, 3)

#define BARR()  __builtin_amdgcn_s_barrier()
#define SB0()   __builtin_amdgcn_sched_barrier(0)
#define LGKM0() do { asm volatile("s_waitcnt lgkmcnt(0)" ::: "memory"); SB0(); } while (0)
#define LGKM4() do { asm volatile("s_waitcnt lgkmcnt(4)" ::: "memory"); SB0(); } while (0)
#define VMC8()  asm volatile("s_waitcnt vmcnt(8)" ::: "memory")
#define PRIO1() __builtin_amdgcn_s_setprio(1)
#define PRIO0() __builtin_amdgcn_s_setprio(0)

// One K-tile (r7 phases). Head VMC8 drains B(t)'s 4 DMAs (leaves the 8 A-glb
// loads of tile t+1 in flight). Tail: cvt+write A(t+1) (compiler inserts the
// precise vmcnt for av), issue A-glb(t+2), drain writes, ready-barrier.
#define KTILE(A0, A1, B0, B1, BSTG, AWP, tnB, tnA) do {                               \
    VMC8(); BARR();                         /* tile t fully landed, all waves */      \
    DSRB(B0, B1);                                                                     \
    DSRA(aq0, 0, A0, A1);                                                             \
    DSRA(aq1, 1, A0, A1);                                                             \
    LGKM4();  PRIO1(); MFMA16(0, aq0); PRIO0();                                       \
    DSRA(aq0, 2, A0, A1);                                                             \
    LGKM4();  PRIO1(); MFMA16(1, aq1); PRIO0();                                       \
    DSRA(aq1, 3, A0, A1);  STAGE_B(BSTG, 0, tnB);                                     \
    LGKM4();  PRIO1(); MFMA16(2, aq0); PRIO0();                                       \
    STAGE_B(BSTG, 1, tnB);                                                            \
    LGKM0();  PRIO1(); MFMA16(3, aq1); PRIO0();                                       \
    WRITE_A(AWP);                           /* A(t+1) -> freed buffer */              \
    LOAD_A(tnA);                            /* A(t+2) f32 -> av */                    \
    LGKM0();                                /* my 4 writes drained */                 \
    BARR();                                 /* buffers ready for t+1 */               \
} while (0)

__global__ __launch_bounds__(512, 2) void gemm_fa(const float* __restrict__ x,
                                                  const _Float16* __restrict__ Wt,
                                                  const float* __restrict__ scale,
                                                  const float* __restrict__ bias,
                                                  float* __restrict__ C) {
    __shared__ __attribute__((aligned(128))) _Float16 As0_[16384];  // [256][64] f16
    __shared__ __attribute__((aligned(128))) _Float16 As1_[16384];
    __shared__ __attribute__((aligned(128))) _Float16 Bs0_[16384];
    __shared__ __attribute__((aligned(128))) _Float16 Bs1_[16384];

    // T1: XCD-aware bijective swizzle (512 blocks, 512 % 8 == 0)
    const int bid = blockIdx.x;
    const int swz = (bid & 7) * 64 + (bid >> 3);
    const int bm  = swz >> 4;            // 0..31
    const int bn  = swz & 15;            // 0..15

    const int t  = threadIdx.x;          // 0..511
    const int l  = t & 63;
    const int w  = t >> 6;               // 8 waves: 2(M) x 4(N)
    const int wm = w >> 2, wn = w & 3;   // wave out: 128 rows x 64 cols
    const int lr = l & 15, lh = l >> 4;

    // B staging source (r7-verified): pre-XOR-swizzled k
    const int rowIdxB = t >> 3;
    const int kbSwB   = ((t & 7) * 16) ^ ((rowIdxB & 7) << 4);
    const _Float16* bStageBase = Wt + (size_t)(bn * 256 + rowIdxB) * K_DIM + (kbSwB >> 1);

    // A reg-staging: thread t owns row t>>1 (0..255), k-half (t&1)*32
    const int arow = t >> 1, akh = t & 1, akh4 = akh * 4;
    const int aswz = (arow & 7) << 4;
    const float* aSrc = x + (size_t)(bm * 256 + arow) * K_DIM + akh * 32;
    char* a0p = (char*)As0_ + arow * 128;
    char* a1p = (char*)As1_ + arow * 128;

    // ds_read addresses (r7 verbatim; 0 conflicts measured)
    const int  mask = (lr & 7) << 4;
    const uint32_t m6   = (uint32_t)(mask & 64);
    const uint32_t aoff = (uint32_t)((wm * 128 + lr) * 128 + ((lh * 16) ^ (mask & 48)));
    const uint32_t boff = (uint32_t)((wn * 64 + lr) * 128 + ((lh * 16) ^ (mask & 48)));
    const uint32_t aA0k0 = (uint32_t)(uintptr_t)As0_ + aoff + m6;
    const uint32_t aA0k1 = (uint32_t)(uintptr_t)As0_ + aoff + (64u ^ m6);
    const uint32_t aA1k0 = (uint32_t)(uintptr_t)As1_ + aoff + m6;
    const uint32_t aA1k1 = (uint32_t)(uintptr_t)As1_ + aoff + (64u ^ m6);
    const uint32_t bB0k0 = (uint32_t)(uintptr_t)Bs0_ + boff + m6;
    const uint32_t bB0k1 = (uint32_t)(uintptr_t)Bs0_ + boff + (64u ^ m6);
    const uint32_t bB1k0 = (uint32_t)(uintptr_t)Bs1_ + boff + m6;
    const uint32_t bB1k1 = (uint32_t)(uintptr_t)Bs1_ + boff + (64u ^ m6);

    f16x8 aq0[2][2], aq1[2][2], bf[4][2];
    float4 av[8];
    f32x4 acc[8][4] = {};

    // prologue: A(0) -> As0_, B(0) DMA -> Bs0_, A(1) f32 -> av
    LOAD_A(0);
    WRITE_A(a0p);
    STAGE_B(Bs0_, 0, 0); STAGE_B(Bs0_, 1, 0);
    LOAD_A(1);
    LGKM0();                    // A(0) writes drained before first barrier

#pragma unroll 1
    for (int it = 0; it < 32; ++it) {             // 64 K-tiles, 2 per iteration
        const int t1 = 2 * it + 1;                // <= 63
        const int t2 = (2 * it + 2) & 63;         // wraps only on last iter
        const int t3 = (2 * it + 3) & 63;
        // tile 2it (parity 0): stage B(t1)->Bs1_, write A(t1)->As1_, load A(t2)
        KTILE(aA0k0, aA0k1, bB0k0, bB0k1, Bs1_, a1p, t1, t2);
        // tile 2it+1 (parity 1): stage B(t2)->Bs0_, write A(t2)->As0_, load A(t3)
        KTILE(aA1k0, aA1k1, bB1k0, bB1k1, Bs0_, a0p, t2, t3);
    }
    asm volatile("s_waitcnt vmcnt(0)" ::: "memory");  // drain dangling prefetches

    // epilogue: C/D layout col = lane&15, row = (lane>>4)*4 + reg  [m89-verified]
    const int col0 = bn * 256 + wn * 64 + lr;
    const int row0 = bm * 256 + wm * 128 + lh * 4;
    float sc[4], bi[4];
#pragma unroll
    for (int ni = 0; ni < 4; ++ni) {
        sc[ni] = scale[col0 + ni * 16];
        bi[ni] = bias[col0 + ni * 16];
    }
#pragma unroll
    for (int ai = 0; ai < 8; ++ai)
#pragma unroll
        for (int r = 0; r < 4; ++r) {
            const size_t rowOff = (size_t)(row0 + ai * 16 + r) * N_DIM;
#pragma unroll
            for (int ni = 0; ni < 4; ++ni)
                C[rowOff + col0 + ni * 16] = acc[ai][ni][r] * sc[ni] + bi[ni];
        }
}

extern "C" void kernel_launch(void* const* d_in, const int* in_sizes, int n_in,
                              void* d_out, int out_size, void* d_ws, size_t ws_size,
                              hipStream_t stream) {
    const float* x     = (const float*)d_in[0];
    const int*   wq    = (const int*)d_in[1];
    const float* scale = (const float*)d_in[2];
    const float* bias  = (const float*)d_in[3];
    float* out = (float*)d_out;

    _Float16* Wt = (_Float16*)d_ws;                 // 33.5 MB (ws >= 100.7MB, r4)
    dim3 tgrid(N_DIM / 64, K_DIM / 64);
    dequant_w_to_f16<<<tgrid, 256, 0, stream>>>(wq, Wt);

    const int nblocks = (M_DIM / 256) * (N_DIM / 256);   // 512
    gemm_fa<<<nblocks, 512, 0, stream>>>(x, Wt, scale, bias, out);
}